// Round 6
// baseline (184.914 us; speedup 1.0000x reference)
//
#include <hip/hip_runtime.h>

// out[e,i] = sum_j mat[e,i,j] v[e,j] + bias[e,i],  [mat|bias] = MLP(pos).reshape(32,33)
// Round-7: depth-2 register prefetch in the barrier-free G-loop.
// r5 finding: depth-1 prefetch leaves ~200cyc L2 latency exposed per tile
// (wall ~280cyc vs 78cyc MFMA issue) and effective residency is ~2 waves/SIMD
// regardless of reported VGPR/LDS headroom -> MfmaUtil stuck at 31%.
// Fix: two B-tile register buffers (bfA/bfB), prefetch depth 2 -> per-tile wall
// ~140cyc -> MFMA-bound at 2 waves/SIMD. Register cost (+16) paid by splitting
// oa accumulator per ih-half (G-loop halves were already sequential): oa[4][4],
// out-write + re-init between halves (once, overlapped with in-flight prefetch).
//   P[e, col] = h2[e,0:128] @ Wpack[0:128, col]   (col = j*32+i; W3-only)
//   out[e,i]  = sum_{col: i} vext[e,j] * P[e,col] + (b3 mini-GEMM)
// LDS = vt only (34320 B). Grid 1024 = 4 blocks/CU of work.
// ws: Wg2 @0 (270336 B), W2f @270336 (32768 B), b3f @303104 (2048 B), b3c @305152 (128 B)

#define E_TOTAL 262144
#define EPB 256
#define NBLK (E_TOTAL / EPB)

typedef float f32x4 __attribute__((ext_vector_type(4)));
typedef short s8v  __attribute__((ext_vector_type(8)));

__device__ __forceinline__ unsigned short f2bf(float x) {
  unsigned u = __float_as_uint(x);
  u += 0x7fffu + ((u >> 16) & 1u);
  return (unsigned short)(u >> 16);
}

// ---------------- prep: pack W2/W3/b3 into MFMA B-fragment order ----------------
__global__ void prep_pack(const float* __restrict__ W2, const float* __restrict__ W3,
                          const float* __restrict__ b3,
                          unsigned short* __restrict__ Wg2, unsigned short* __restrict__ W2f,
                          unsigned short* __restrict__ b3f, float* __restrict__ b3c) {
  int idx = blockIdx.x * 256 + threadIdx.x;   // 528 blocks cover 135168
  if (idx < 135168) {
    // Wg2[((nn*4+ks)*64 + lane)*8 + jj] : B[k=ks*32+(lane>>4)*8+jj][col]
    // nn is the PERMUTED tile order: nn<33 -> tile 2*nn (ih=0), else tile 2*(nn-33)+1 (ih=1)
    int jj = idx & 7, lane = (idx >> 3) & 63;
    int ksnn = idx >> 9, ks = ksnn & 3, nn = ksnn >> 2;
    int nnt = (nn < 33) ? (2 * nn) : (2 * (nn - 33) + 1);
    int k = ks * 32 + ((lane >> 4) << 3) + jj;
    int col = nnt * 16 + (lane & 15);        // col = j*32 + i
    int i = col & 31, j = col >> 5;
    Wg2[idx] = f2bf(W3[k * 1056 + i * 33 + j]);
  }
  if (idx < 16384) {
    // W2f[((ks*8+nt)*64 + lane)*8 + jj]: n=nt*16+(lane&15), k=ks*32+(lane>>4)*8+jj
    int ks = idx >> 12, nt = (idx >> 9) & 7, l = (idx >> 3) & 63, jj = idx & 7;
    int k = ks * 32 + ((l >> 4) << 3) + jj;
    int n = nt * 16 + (l & 15);
    W2f[idx] = f2bf(W2[k * 128 + n]);
  }
  if (idx < 1024) {
    // b3f[(ih*64+lane)*8+jj]: B[k=j][n=i] = b3[i*33+j], j<32
    int jj = idx & 7, lane = (idx >> 3) & 63, ih = idx >> 9;
    int j = ((lane >> 4) << 3) + jj, i = ih * 16 + (lane & 15);
    b3f[idx] = f2bf(b3[i * 33 + j]);
  }
  if (idx < 32) b3c[idx] = b3[idx * 33 + 32];
}

// ---------------- G-loop helpers (register-resident B, direct from L2) ----------------
__device__ __forceinline__ void tile_load(s8v (&dst)[4], const unsigned short* __restrict__ Wg2,
                                          int n, int lane) {
  // frag ks of tile n: Wg2[(n*4+ks)*512 + lane*8], 16 B/lane, coalesced dwordx4;
  // 4 loads share one base, imm offsets 0/1024/2048/3072.
  const s8v* src = (const s8v*)(Wg2 + (size_t)n * 2048 + lane * 8);
#pragma unroll
  for (int ks = 0; ks < 4; ++ks) dst[ks] = src[ks * 64];
}

__device__ __forceinline__ void tile_compute(const s8v (&bf)[4], const float* __restrict__ vt,
                                             int j, int eoff,
                                             const s8v (&af)[4][4], float (&oa)[4][4]) {
  const f32x4 zero4 = {0.f, 0.f, 0.f, 0.f};
  const float* vp = vt + j * 260 + eoff;
#pragma unroll
  for (int m = 0; m < 4; ++m) {
    f32x4 vv = *(const f32x4*)(vp + m * 16);  // 16-lane broadcast, independent of bf
    f32x4 p = __builtin_amdgcn_mfma_f32_16x16x32_bf16(af[m][0], bf[0], zero4, 0, 0, 0);
#pragma unroll
    for (int ks = 1; ks < 4; ++ks)
      p = __builtin_amdgcn_mfma_f32_16x16x32_bf16(af[m][ks], bf[ks], p, 0, 0, 0);
#pragma unroll
    for (int r = 0; r < 4; ++r) oa[m][r] += vv[r] * p[r];
  }
}

// oa[m][r] = sum_j v[e,j] b3[i*33+j] + b3[i*33+32], for the given ih half
__device__ __forceinline__ void init_oa(float (&oa)[4][4], const float* __restrict__ vj,
                                        const unsigned short* __restrict__ b3f,
                                        const float* __restrict__ b3c,
                                        int B0, int w, int q, int ln, int lane, int ih) {
  s8v b3fr = *(const s8v*)(b3f + (ih * 64 + lane) * 8);
  float cbv = b3c[ih * 16 + ln];
  f32x4 ci = {cbv, cbv, cbv, cbv};
#pragma unroll
  for (int m = 0; m < 4; ++m) {
    int e = B0 + w * 64 + m * 16 + ln;
    const float4 va = *(const float4*)(vj + (size_t)e * 32 + q * 8);
    const float4 vb = *(const float4*)(vj + (size_t)e * 32 + q * 8 + 4);
    s8v t;
    t[0] = (short)f2bf(va.x); t[1] = (short)f2bf(va.y);
    t[2] = (short)f2bf(va.z); t[3] = (short)f2bf(va.w);
    t[4] = (short)f2bf(vb.x); t[5] = (short)f2bf(vb.y);
    t[6] = (short)f2bf(vb.z); t[7] = (short)f2bf(vb.w);
    f32x4 p = __builtin_amdgcn_mfma_f32_16x16x32_bf16(t, b3fr, ci, 0, 0, 0);
#pragma unroll
    for (int r = 0; r < 4; ++r) oa[m][r] = p[r];
  }
}

__device__ __forceinline__ void store_half(float* __restrict__ out, const float (&oa)[4][4],
                                           int B0, int w, int q, int ln, int ih) {
#pragma unroll
  for (int m = 0; m < 4; ++m)
#pragma unroll
    for (int r = 0; r < 4; ++r) {
      int e = B0 + w * 64 + m * 16 + q * 4 + r;
      out[(size_t)e * 32 + ih * 16 + ln] = oa[m][r];
    }
}

// ---------------- fused main kernel ----------------
// 256 threads (4 waves), 256 edges/block; wave w owns edges [B0+w*64, B0+w*64+64).
// LDS (overlapped phases):
//   prologue: h2n u16[64][136] @0 (17408), h1c u16[32][136] @17408 (8704)
//   G-loop:   vt f32[33][260] @0 (34320)
__global__ __launch_bounds__(256, 2) void fnn_fused(
    const float* __restrict__ pos_i, const float* __restrict__ pos_j,
    const float* __restrict__ vj, const float* __restrict__ W1,
    const float* __restrict__ b1, const float* __restrict__ b2,
    const unsigned short* __restrict__ W2f, const unsigned short* __restrict__ Wg2,
    const unsigned short* __restrict__ b3f, const float* __restrict__ b3c,
    float* __restrict__ out) {
  __shared__ __attribute__((aligned(16))) char smem[34320];
  float* vt = (float*)smem;                                  // [33][260], G-loop phase
  unsigned short* h2n = (unsigned short*)smem;               // [64][136], prologue phase
  unsigned short* h1c = (unsigned short*)(smem + 17408);     // [32][136], prologue phase

  const int tid = threadIdx.x;
  const int w = tid >> 6, lane = tid & 63, q = lane >> 4, ln = lane & 15;
  const int B0 = blockIdx.x * EPB;
  const int eoff = w * 64 + q * 4;

  // --- out-acc init for ih=0 half ---
  float oa[4][4];
  init_oa(oa, vj, b3f, b3c, B0, w, q, ln, lane, 0);

  // --- W1/b1 register slice: thread owns 8 hidden cols for stage 1 ---
  const int hh0 = (tid & 15) * 8;
  float w1r[4][8], b1r[8];
#pragma unroll
  for (int d = 0; d < 4; ++d)
#pragma unroll
    for (int u = 0; u < 8; ++u) w1r[d][u] = W1[d * 128 + hh0 + u];
#pragma unroll
  for (int u = 0; u < 8; ++u) b1r[u] = b1[hh0 + u];

  // --- stages 1+2 per quarter (64 edges), extract A-frags to registers ---
  s8v af[4][4];
  for (int qtr = 0; qtr < 4; ++qtr) {
    for (int cb = 0; cb < 2; ++cb) {
#pragma unroll
      for (int half = 0; half < 2; ++half) {
        int ee = (tid >> 4) + half * 16;
        int eg = B0 + qtr * 64 + cb * 32 + ee;
        float2 pi = *(const float2*)(pos_i + (size_t)eg * 2);
        float2 pj = *(const float2*)(pos_j + (size_t)eg * 2);
        s8v hv;
#pragma unroll
        for (int u = 0; u < 8; ++u) {
          float o = b1r[u] + pi.x * w1r[0][u] + pi.y * w1r[1][u] +
                    pj.x * w1r[2][u] + pj.y * w1r[3][u];
          hv[u] = (short)f2bf(fmaxf(o, 0.f));
        }
        *(s8v*)&h1c[ee * 136 + hh0] = hv;
      }
      __syncthreads();
#pragma unroll
      for (int s = 0; s < 4; ++s) {
        int tt = w * 4 + s, mt = tt >> 3, nt = tt & 7;
        f32x4 a4 = {0.f, 0.f, 0.f, 0.f};
#pragma unroll
        for (int ks = 0; ks < 4; ++ks) {
          s8v afr = *(const s8v*)&h1c[(mt * 16 + ln) * 136 + ks * 32 + q * 8];
          s8v bfr = *(const s8v*)(W2f + ((ks * 8 + nt) * 64 + lane) * 8);
          a4 = __builtin_amdgcn_mfma_f32_16x16x32_bf16(afr, bfr, a4, 0, 0, 0);
        }
        float b2v = b2[nt * 16 + ln];
        int eb = cb * 32 + mt * 16 + q * 4;
        int kc = nt * 16 + ln;
#pragma unroll
        for (int r = 0; r < 4; ++r)
          h2n[(eb + r) * 136 + kc] = f2bf(fmaxf(a4[r] + b2v, 0.f));
      }
      __syncthreads();
    }
    if (w == qtr) {
#pragma unroll
      for (int m = 0; m < 4; ++m)
#pragma unroll
        for (int ks = 0; ks < 4; ++ks)
          af[m][ks] = *(const s8v*)&h2n[(m * 16 + ln) * 136 + ks * 32 + q * 8];
    }
    __syncthreads();   // last cross-wave dep: h2n reads drained before vt overwrite
  }

  // --- prime B tiles 0,1 (register double-buffer) while vt is being built ---
  s8v bfA[4], bfB[4];
  tile_load(bfA, Wg2, 0, lane);
  tile_load(bfB, Wg2, 1, lane);

  // --- build vt: vt[j][e] = v[e,j] (f32), row 32 = 1.0 (overwrites h1c/h2n region) ---
  // Wave w writes ONLY columns [w*64, w*64+64) and reads ONLY those columns in the
  // G-loop -> no cross-wave dependency -> NO barrier needed from here on.
  {
    const float* vrow = vj + (size_t)(B0 + tid) * 32;
#pragma unroll
    for (int j4 = 0; j4 < 8; ++j4) {
      float4 vv = *(const float4*)(vrow + j4 * 4);
      vt[(j4 * 4 + 0) * 260 + tid] = vv.x;
      vt[(j4 * 4 + 1) * 260 + tid] = vv.y;
      vt[(j4 * 4 + 2) * 260 + tid] = vv.z;
      vt[(j4 * 4 + 3) * 260 + tid] = vv.w;
    }
    vt[32 * 260 + tid] = 1.0f;
  }

  // --- G-loop half 0: tiles 0..32 (j = tile), depth-2 prefetch, zero barriers ---
#pragma unroll 1
  for (int c = 0; c < 16; ++c) {
    tile_compute(bfA, vt, 2 * c,     eoff, af, oa);
    tile_load(bfA, Wg2, 2 * c + 2, lane);
    tile_compute(bfB, vt, 2 * c + 1, eoff, af, oa);
    tile_load(bfB, Wg2, 2 * c + 3, lane);
  }
  tile_compute(bfA, vt, 32, eoff, af, oa);   // tile 32 (bfB holds tile 33)
  tile_load(bfA, Wg2, 34, lane);             // prefetch tile 34 across the half switch

  // --- half switch: write ih=0, re-init oa for ih=1 (overlaps in-flight prefetch) ---
  store_half(out, oa, B0, w, q, ln, 0);
  init_oa(oa, vj, b3f, b3c, B0, w, q, ln, lane, 1);

  // --- G-loop half 1: tiles 33..65 (j = tile-33) ---
#pragma unroll 1
  for (int c = 0; c < 16; ++c) {
    tile_compute(bfB, vt, 2 * c,     eoff, af, oa);   // tile 33+2c
    tile_load(bfB, Wg2, 35 + 2 * c, lane);
    tile_compute(bfA, vt, 2 * c + 1, eoff, af, oa);   // tile 34+2c
    tile_load(bfA, Wg2, 36 + 2 * c, lane);            // c=15 -> tile 66 = pad overread (W2f region)
  }
  tile_compute(bfB, vt, 32, eoff, af, oa);   // tile 65
  store_half(out, oa, B0, w, q, ln, 1);
}

extern "C" void kernel_launch(void* const* d_in, const int* in_sizes, int n_in,
                              void* d_out, int out_size, void* d_ws, size_t ws_size,
                              hipStream_t stream) {
  const float* pos_i = (const float*)d_in[0];
  const float* pos_j = (const float*)d_in[1];
  const float* vj    = (const float*)d_in[2];
  const float* W1    = (const float*)d_in[3];
  const float* b1    = (const float*)d_in[4];
  const float* W2    = (const float*)d_in[5];
  const float* b2    = (const float*)d_in[6];
  const float* W3    = (const float*)d_in[7];
  const float* b3    = (const float*)d_in[8];
  float* outp = (float*)d_out;

  unsigned short* Wg2 = (unsigned short*)d_ws;
  unsigned short* W2f = (unsigned short*)((char*)d_ws + 270336);
  unsigned short* b3f = (unsigned short*)((char*)d_ws + 303104);
  float*          b3c = (float*)((char*)d_ws + 305152);

  prep_pack<<<528, 256, 0, stream>>>(W2, W3, b3, Wg2, W2f, b3f, b3c);
  fnn_fused<<<NBLK, 256, 0, stream>>>(pos_i, pos_j, vj, W1, b1, b2, W2f, Wg2, b3f, b3c, outp);
}

// Round 7
// 178.727 us; speedup vs baseline: 1.0346x; 1.0346x over previous
//
#include <hip/hip_runtime.h>

// out[e,i] = sum_j mat[e,i,j] v[e,j] + bias[e,i],  [mat|bias] = MLP(pos).reshape(32,33)
// Round-8: dependent-MFMA interleave.
// r4/r5/r6 invariance (three G-loop structures, identical 105us / MfmaUtil 31%)
// falsified latency-hiding theories. Pipe arithmetic: 16x16x32 MFMA = ~16 cyc/SIMD
// throughput; kernel MFMA floor ~32us; measured 105us @ 31% util -> pipe idles with
// operands resident. Hypothesis: dependent-MFMA issue latency D~40-60cyc; the m-outer
// chain (4 back-to-back dependent MFMAs) caps per-wave issue at 16 MFMA / 16D cyc.
// Fix: ks-outer / m-inner with p[4] live -> dependent distance 4 issue slots.
// Depth-1 prefetch (depth proven irrelevant) keeps peak regs ~124 <= 128 cap.
// Also: prep_pack inverted to coalesced W3/W2 reads + scattered bf16 writes.
//   P[e, col] = h2[e,0:128] @ Wpack[0:128, col]   (col = j*32+i; W3-only)
//   out[e,i]  = sum_{col: i} vext[e,j] * P[e,col] + (b3 mini-GEMM)
// LDS = vt only (34320 B). Grid 1024 = 4 blocks/CU of work.
// ws: Wg2 @0 (270336 B), W2f @270336 (32768 B), b3f @303104 (2048 B), b3c @305152 (128 B)

#define E_TOTAL 262144
#define EPB 256
#define NBLK (E_TOTAL / EPB)

typedef float f32x4 __attribute__((ext_vector_type(4)));
typedef short s8v  __attribute__((ext_vector_type(8)));

__device__ __forceinline__ unsigned short f2bf(float x) {
  unsigned u = __float_as_uint(x);
  u += 0x7fffu + ((u >> 16) & 1u);
  return (unsigned short)(u >> 16);
}

// ---------------- prep: pack W2/W3/b3 into MFMA B-fragment order ----------------
// Inverted vs rounds 0-7: enumerate the SOURCE linearly (coalesced f32 reads),
// scatter the bf16 writes (stores don't stall).
__global__ void prep_pack(const float* __restrict__ W2, const float* __restrict__ W3,
                          const float* __restrict__ b3,
                          unsigned short* __restrict__ Wg2, unsigned short* __restrict__ W2f,
                          unsigned short* __restrict__ b3f, float* __restrict__ b3c) {
  int idx = blockIdx.x * 256 + threadIdx.x;   // 528 blocks cover 135168
  if (idx < 135168) {
    // src: W3[k][c], k = idx/1056, c = idx%1056, c = i*33 + jc (jc=32 -> W3-bias col)
    int k = idx / 1056, c = idx % 1056;
    int i = c / 33, jc = c % 33;
    int col = jc * 32 + i;                    // Wg2 col = j*32 + i
    int nnt = col >> 4, low = col & 15;
    int nn = (nnt & 1) ? (33 + (nnt >> 1)) : (nnt >> 1);   // permuted tile order
    int ks = k >> 5, kr = k & 31;
    int lane = ((kr >> 3) << 4) + low;
    int jj = k & 7;
    int dst = ((nn * 4 + ks) * 64 + lane) * 8 + jj;
    Wg2[dst] = f2bf(W3[idx]);
  }
  if (idx < 16384) {
    // src: W2[k][n], k = idx>>7, n = idx&127
    int k = idx >> 7, n = idx & 127;
    int ks = k >> 5, kr = k & 31;
    int nt = n >> 4, low = n & 15;
    int l = ((kr >> 3) << 4) + low;
    int jj = k & 7;
    int dst = ((ks * 8 + nt) * 64 + l) * 8 + jj;
    W2f[dst] = f2bf(W2[idx]);
  }
  if (idx < 1024) {
    // b3f[(ih*64+lane)*8+jj]: B[k=j][n=i] = b3[i*33+j], j<32
    int jj = idx & 7, lane = (idx >> 3) & 63, ih = idx >> 9;
    int j = ((lane >> 4) << 3) + jj, i = ih * 16 + (lane & 15);
    b3f[idx] = f2bf(b3[i * 33 + j]);
  }
  if (idx < 32) b3c[idx] = b3[idx * 33 + 32];
}

// ---------------- G-loop helpers (register-resident B, direct from L2) ----------------
__device__ __forceinline__ void tile_load(s8v (&dst)[4], const unsigned short* __restrict__ Wg2,
                                          int n, int lane) {
  // frag ks of tile n: Wg2[(n*4+ks)*512 + lane*8], 16 B/lane, coalesced dwordx4;
  // 4 loads share one base, imm offsets 0/1024/2048/3072.
  const s8v* src = (const s8v*)(Wg2 + (size_t)n * 2048 + lane * 8);
#pragma unroll
  for (int ks = 0; ks < 4; ++ks) dst[ks] = src[ks * 64];
}

// ks-outer / m-inner: consecutive DEPENDENT MFMAs are 4 issue slots apart.
__device__ __forceinline__ void tile_compute(const s8v (&bf)[4], const float* __restrict__ vt,
                                             int j, int eoff,
                                             const s8v (&af)[4][4], float (&oa)[4][4]) {
  const f32x4 zero4 = {0.f, 0.f, 0.f, 0.f};
  const float* vp = vt + j * 260 + eoff;
  f32x4 p[4];
#pragma unroll
  for (int m = 0; m < 4; ++m)
    p[m] = __builtin_amdgcn_mfma_f32_16x16x32_bf16(af[m][0], bf[0], zero4, 0, 0, 0);
#pragma unroll
  for (int ks = 1; ks < 4; ++ks)
#pragma unroll
    for (int m = 0; m < 4; ++m)
      p[m] = __builtin_amdgcn_mfma_f32_16x16x32_bf16(af[m][ks], bf[ks], p[m], 0, 0, 0);
#pragma unroll
  for (int m = 0; m < 4; ++m) {
    f32x4 vv = *(const f32x4*)(vp + m * 16);  // 16-lane broadcast, conflict-free
#pragma unroll
    for (int r = 0; r < 4; ++r) oa[m][r] += vv[r] * p[m][r];
  }
}

// oa[m][r] = sum_j v[e,j] b3[i*33+j] + b3[i*33+32], for the given ih half
__device__ __forceinline__ void init_oa(float (&oa)[4][4], const float* __restrict__ vj,
                                        const unsigned short* __restrict__ b3f,
                                        const float* __restrict__ b3c,
                                        int B0, int w, int q, int ln, int lane, int ih) {
  s8v b3fr = *(const s8v*)(b3f + (ih * 64 + lane) * 8);
  float cbv = b3c[ih * 16 + ln];
  f32x4 ci = {cbv, cbv, cbv, cbv};
#pragma unroll
  for (int m = 0; m < 4; ++m) {
    int e = B0 + w * 64 + m * 16 + ln;
    const float4 va = *(const float4*)(vj + (size_t)e * 32 + q * 8);
    const float4 vb = *(const float4*)(vj + (size_t)e * 32 + q * 8 + 4);
    s8v t;
    t[0] = (short)f2bf(va.x); t[1] = (short)f2bf(va.y);
    t[2] = (short)f2bf(va.z); t[3] = (short)f2bf(va.w);
    t[4] = (short)f2bf(vb.x); t[5] = (short)f2bf(vb.y);
    t[6] = (short)f2bf(vb.z); t[7] = (short)f2bf(vb.w);
    f32x4 p = __builtin_amdgcn_mfma_f32_16x16x32_bf16(t, b3fr, ci, 0, 0, 0);
#pragma unroll
    for (int r = 0; r < 4; ++r) oa[m][r] = p[r];
  }
}

__device__ __forceinline__ void store_half(float* __restrict__ out, const float (&oa)[4][4],
                                           int B0, int w, int q, int ln, int ih) {
#pragma unroll
  for (int m = 0; m < 4; ++m)
#pragma unroll
    for (int r = 0; r < 4; ++r) {
      int e = B0 + w * 64 + m * 16 + q * 4 + r;
      out[(size_t)e * 32 + ih * 16 + ln] = oa[m][r];
    }
}

// ---------------- fused main kernel ----------------
// 256 threads (4 waves), 256 edges/block; wave w owns edges [B0+w*64, B0+w*64+64).
// LDS (overlapped phases):
//   prologue: h2n u16[64][136] @0 (17408), h1c u16[32][136] @17408 (8704)
//   G-loop:   vt f32[33][260] @0 (34320)
__global__ __launch_bounds__(256, 2) void fnn_fused(
    const float* __restrict__ pos_i, const float* __restrict__ pos_j,
    const float* __restrict__ vj, const float* __restrict__ W1,
    const float* __restrict__ b1, const float* __restrict__ b2,
    const unsigned short* __restrict__ W2f, const unsigned short* __restrict__ Wg2,
    const unsigned short* __restrict__ b3f, const float* __restrict__ b3c,
    float* __restrict__ out) {
  __shared__ __attribute__((aligned(16))) char smem[34320];
  float* vt = (float*)smem;                                  // [33][260], G-loop phase
  unsigned short* h2n = (unsigned short*)smem;               // [64][136], prologue phase
  unsigned short* h1c = (unsigned short*)(smem + 17408);     // [32][136], prologue phase

  const int tid = threadIdx.x;
  const int w = tid >> 6, lane = tid & 63, q = lane >> 4, ln = lane & 15;
  const int B0 = blockIdx.x * EPB;
  const int eoff = w * 64 + q * 4;

  // --- out-acc init for ih=0 half ---
  float oa[4][4];
  init_oa(oa, vj, b3f, b3c, B0, w, q, ln, lane, 0);

  // --- W1/b1 register slice: thread owns 8 hidden cols for stage 1 ---
  const int hh0 = (tid & 15) * 8;
  float w1r[4][8], b1r[8];
#pragma unroll
  for (int d = 0; d < 4; ++d)
#pragma unroll
    for (int u = 0; u < 8; ++u) w1r[d][u] = W1[d * 128 + hh0 + u];
#pragma unroll
  for (int u = 0; u < 8; ++u) b1r[u] = b1[hh0 + u];

  // --- stages 1+2 per quarter (64 edges), extract A-frags to registers ---
  s8v af[4][4];
  for (int qtr = 0; qtr < 4; ++qtr) {
    for (int cb = 0; cb < 2; ++cb) {
#pragma unroll
      for (int half = 0; half < 2; ++half) {
        int ee = (tid >> 4) + half * 16;
        int eg = B0 + qtr * 64 + cb * 32 + ee;
        float2 pi = *(const float2*)(pos_i + (size_t)eg * 2);
        float2 pj = *(const float2*)(pos_j + (size_t)eg * 2);
        s8v hv;
#pragma unroll
        for (int u = 0; u < 8; ++u) {
          float o = b1r[u] + pi.x * w1r[0][u] + pi.y * w1r[1][u] +
                    pj.x * w1r[2][u] + pj.y * w1r[3][u];
          hv[u] = (short)f2bf(fmaxf(o, 0.f));
        }
        *(s8v*)&h1c[ee * 136 + hh0] = hv;
      }
      __syncthreads();
#pragma unroll
      for (int s = 0; s < 4; ++s) {
        int tt = w * 4 + s, mt = tt >> 3, nt = tt & 7;
        f32x4 a4 = {0.f, 0.f, 0.f, 0.f};
#pragma unroll
        for (int ks = 0; ks < 4; ++ks) {
          s8v afr = *(const s8v*)&h1c[(mt * 16 + ln) * 136 + ks * 32 + q * 8];
          s8v bfr = *(const s8v*)(W2f + ((ks * 8 + nt) * 64 + lane) * 8);
          a4 = __builtin_amdgcn_mfma_f32_16x16x32_bf16(afr, bfr, a4, 0, 0, 0);
        }
        float b2v = b2[nt * 16 + ln];
        int eb = cb * 32 + mt * 16 + q * 4;
        int kc = nt * 16 + ln;
#pragma unroll
        for (int r = 0; r < 4; ++r)
          h2n[(eb + r) * 136 + kc] = f2bf(fmaxf(a4[r] + b2v, 0.f));
      }
      __syncthreads();
    }
    if (w == qtr) {
#pragma unroll
      for (int m = 0; m < 4; ++m)
#pragma unroll
        for (int ks = 0; ks < 4; ++ks)
          af[m][ks] = *(const s8v*)&h2n[(m * 16 + ln) * 136 + ks * 32 + q * 8];
    }
    __syncthreads();   // last cross-wave dep: h2n reads drained before vt overwrite
  }

  // --- prime B tile 0 (register buffer) while vt is being built ---
  s8v bf[4];
  tile_load(bf, Wg2, 0, lane);

  // --- build vt: vt[j][e] = v[e,j] (f32), row 32 = 1.0 (overwrites h1c/h2n region) ---
  // Wave w writes ONLY columns [w*64, w*64+64) and reads ONLY those columns in the
  // G-loop -> no cross-wave dependency -> NO barrier needed from here on.
  {
    const float* vrow = vj + (size_t)(B0 + tid) * 32;
#pragma unroll
    for (int j4 = 0; j4 < 8; ++j4) {
      float4 vv = *(const float4*)(vrow + j4 * 4);
      vt[(j4 * 4 + 0) * 260 + tid] = vv.x;
      vt[(j4 * 4 + 1) * 260 + tid] = vv.y;
      vt[(j4 * 4 + 2) * 260 + tid] = vv.z;
      vt[(j4 * 4 + 3) * 260 + tid] = vv.w;
    }
    vt[32 * 260 + tid] = 1.0f;
  }

  // --- G-loop half 0: tiles 0..32 (j = tile), depth-1 prefetch, zero barriers ---
#pragma unroll 1
  for (int n = 0; n < 33; ++n) {
    tile_compute(bf, vt, n, eoff, af, oa);
    tile_load(bf, Wg2, n + 1, lane);
  }

  // --- half switch: write ih=0, re-init oa for ih=1 (overlaps in-flight prefetch) ---
  store_half(out, oa, B0, w, q, ln, 0);
  init_oa(oa, vj, b3f, b3c, B0, w, q, ln, lane, 1);

  // --- G-loop half 1: tiles 33..65 (j = tile-33) ---
#pragma unroll 1
  for (int n = 33; n < 66; ++n) {
    tile_compute(bf, vt, n - 33, eoff, af, oa);
    tile_load(bf, Wg2, n + 1, lane);   // n=65 -> tile 66 = pad overread (W2f region), unused
  }
  store_half(out, oa, B0, w, q, ln, 1);
}

extern "C" void kernel_launch(void* const* d_in, const int* in_sizes, int n_in,
                              void* d_out, int out_size, void* d_ws, size_t ws_size,
                              hipStream_t stream) {
  const float* pos_i = (const float*)d_in[0];
  const float* pos_j = (const float*)d_in[1];
  const float* vj    = (const float*)d_in[2];
  const float* W1    = (const float*)d_in[3];
  const float* b1    = (const float*)d_in[4];
  const float* W2    = (const float*)d_in[5];
  const float* b2    = (const float*)d_in[6];
  const float* W3    = (const float*)d_in[7];
  const float* b3    = (const float*)d_in[8];
  float* outp = (float*)d_out;

  unsigned short* Wg2 = (unsigned short*)d_ws;
  unsigned short* W2f = (unsigned short*)((char*)d_ws + 270336);
  unsigned short* b3f = (unsigned short*)((char*)d_ws + 303104);
  float*          b3c = (float*)((char*)d_ws + 305152);

  prep_pack<<<528, 256, 0, stream>>>(W2, W3, b3, Wg2, W2f, b3f, b3c);
  fnn_fused<<<NBLK, 256, 0, stream>>>(pos_i, pos_j, vj, W1, b1, b2, W2f, Wg2, b3f, b3c, outp);
}